// Round 2
// baseline (20722.520 us; speedup 1.0000x reference)
//
#include <hip/hip_runtime.h>
#include <hip/hip_cooperative_groups.h>

namespace cg = cooperative_groups;

typedef _Float16 f16;
typedef __attribute__((ext_vector_type(8))) _Float16 f16x8;
typedef __attribute__((ext_vector_type(4))) float f32x4;

#define NWG      256
#define NTHREADS 768   // 12 waves
#define BB       64
#define TT       512
#define HH       1024
#define HD4      4096
#define VOCABB   128
#define EMBD     128

// LDS layout (bytes)
#define OFF_U0   0        // [16][1024] f16, XOR-swizzled rows : 32768
#define OFF_W1U1 32768    // [16][2048] f16, XOR-swizzled rows : 65536
#define OFF_TW0  98304    // [128][16] f32 : 8192
#define OFF_B1   106496   // [16] f32 : 64
#define OFF_Z0   106560   // [2][64][16] f32 : 8192
#define OFF_Z1A  114752   // [2][64][16] f32 : 8192
#define OFF_Z1B  122944   // [64][16] f32 : 4096   (ends 127040)
#define OFF_WDC  98304    // phase-C alias: [128][128] f16 swizzled : 32768 (ends 131072)
#define SMEM_BYTES 131072

__device__ __forceinline__ float sigf(float x) { return 1.f / (1.f + __expf(-x)); }

// swizzled f16 LDS byte offset: row-major [rows][K], rowstride bytes, XOR bits 4..6
__device__ __forceinline__ int swz(int base, int row, int rowstride, int k) {
    return base + row * rowstride + ((2 * k) ^ ((row & 7) << 4));
}

__global__ __launch_bounds__(NTHREADS, 3)
void lstm_fused(const int* __restrict__ tokens, const float* __restrict__ emb,
                const float* __restrict__ W0, const float* __restrict__ U0,
                const float* __restrict__ b0, const float* __restrict__ W1,
                const float* __restrict__ U1, const float* __restrict__ b1,
                const float* __restrict__ Wd, const float* __restrict__ bd,
                f16* __restrict__ wsh, float* __restrict__ out)
{
    extern __shared__ char smem[];
    cg::grid_group grid = cg::this_grid();
    const int g    = blockIdx.x;    // 0..255, owns gate-cols {gate*1024 + 4g + d}
    const int tid  = threadIdx.x;
    const int lane = tid & 63;
    const int wave = tid >> 6;

    // workspace (f16 units)
    f16* h1seq = wsh;                              // [B][T][H]
    f16* h0st  = wsh + (size_t)BB * TT * HH;       // [2][B][H]
    f16* h1st  = h0st + 2 * BB * HH;               // [2][B][H]

    // ---------------- Phase A: init ----------------
    {   // zero h-state double buffers (4*B*H f16 = 131072 u32; 512 u32 per WG)
        unsigned int* zp = (unsigned int*)h0st;
        for (int i = tid; i < 512; i += NTHREADS) zp[g * 512 + i] = 0u;
    }
    {   // stage U0 / [W1;U1] column slices into LDS as f16, transposed+swizzled
        const int c = tid & 15;                       // local col: gate*4 + delta
        const int orig = ((c >> 2) * HH) + 4 * g + (c & 3);
        for (int k = tid >> 4; k < HH; k += 48) {
            *(f16*)(smem + swz(OFF_U0, c, 2048, k))        = (f16)U0[(size_t)k * HD4 + orig];
            *(f16*)(smem + swz(OFF_W1U1, c, 4096, k))      = (f16)W1[(size_t)k * HD4 + orig];
            *(f16*)(smem + swz(OFF_W1U1, c, 4096, k + HH)) = (f16)U1[(size_t)k * HD4 + orig];
        }
        if (tid < 16)
            ((float*)(smem + OFF_B1))[tid] = b1[((tid >> 2) * HH) + 4 * g + (tid & 3)];
    }
    // TW0 = emb @ W0 + b0, our 16-column slice (f32, exact)
    for (int idx = tid; idx < VOCABB * 16; idx += NTHREADS) {
        int v = idx >> 4, c = idx & 15;
        int orig = ((c >> 2) * HH) + 4 * g + (c & 3);
        float acc = b0[orig];
        for (int e = 0; e < EMBD; ++e)
            acc += emb[v * EMBD + e] * W0[(size_t)e * HD4 + orig];
        ((float*)(smem + OFF_TW0))[idx] = acc;
    }
    __syncthreads();
    grid.sync();

    // ---------------- Phase B: 513 pipelined supersteps ----------------
    float c0 = 0.f, c1 = 0.f;                 // cell states in gate-thread regs
    const int gb = tid >> 2, gd = tid & 3;    // gate thread: batch, delta
    float* z0buf  = (float*)(smem + OFF_Z0);
    float* z1abuf = (float*)(smem + OFF_Z1A);
    float* z1bbuf = (float*)(smem + OFF_Z1B);
    float* TW0s   = (float*)(smem + OFF_TW0);
    float* b1s    = (float*)(smem + OFF_B1);

    for (int s = 0; s <= TT; ++s) {
        const f16* h0r = h0st + (size_t)(s & 1) * BB * HH;
        const f16* h1r = h1st + (size_t)(s & 1) * BB * HH;
        const int n  = lane & 15;
        const int kq = 8 * (lane >> 4);

        if (wave < 8) {
            // h0 path: shared A-fragment feeds U0 (layer0) and W1 (layer1)
            const int mt = wave & 3, kh = wave >> 2;
            const int arow = mt * 16 + (lane & 15);
            f32x4 a0 = {0.f, 0.f, 0.f, 0.f}, a1 = {0.f, 0.f, 0.f, 0.f};
            #pragma unroll 4
            for (int ki = 0; ki < 16; ++ki) {
                int k = kh * 512 + ki * 32 + kq;
                f16x8 av  = *(const f16x8*)&h0r[(size_t)arow * HH + k];
                f16x8 bv0 = *(const f16x8*)(smem + swz(OFF_U0, n, 2048, k));
                a0 = __builtin_amdgcn_mfma_f32_16x16x32_f16(av, bv0, a0, 0, 0, 0);
                f16x8 bv1 = *(const f16x8*)(smem + swz(OFF_W1U1, n, 4096, k));
                a1 = __builtin_amdgcn_mfma_f32_16x16x32_f16(av, bv1, a1, 0, 0, 0);
            }
            int r0 = mt * 16 + (lane >> 4) * 4;
            #pragma unroll
            for (int r = 0; r < 4; ++r) {
                z0buf [(kh * 64 + r0 + r) * 16 + n] = a0[r];
                z1abuf[(kh * 64 + r0 + r) * 16 + n] = a1[r];
            }
        } else {
            // h1 path: h1_{t-1} @ U1
            const int mt = wave & 3;
            const int arow = mt * 16 + (lane & 15);
            f32x4 a1 = {0.f, 0.f, 0.f, 0.f};
            #pragma unroll 4
            for (int ki = 0; ki < 32; ++ki) {
                int k = ki * 32 + kq;
                f16x8 av = *(const f16x8*)&h1r[(size_t)arow * HH + k];
                f16x8 bv = *(const f16x8*)(smem + swz(OFF_W1U1, n, 4096, k + HH));
                a1 = __builtin_amdgcn_mfma_f32_16x16x32_f16(av, bv, a1, 0, 0, 0);
            }
            int r0 = mt * 16 + (lane >> 4) * 4;
            #pragma unroll
            for (int r = 0; r < 4; ++r) z1bbuf[(r0 + r) * 16 + n] = a1[r];
        }
        __syncthreads();

        if (tid < 256) {
            const int j = 4 * g + gd;
            if (s < TT) {   // layer 0, step t = s
                int tok = tokens[gb * TT + s];
                float zi = z0buf[gb * 16 +  0 + gd] + z0buf[(64 + gb) * 16 +  0 + gd] + TW0s[tok * 16 +  0 + gd];
                float zf = z0buf[gb * 16 +  4 + gd] + z0buf[(64 + gb) * 16 +  4 + gd] + TW0s[tok * 16 +  4 + gd];
                float zg = z0buf[gb * 16 +  8 + gd] + z0buf[(64 + gb) * 16 +  8 + gd] + TW0s[tok * 16 +  8 + gd];
                float zo = z0buf[gb * 16 + 12 + gd] + z0buf[(64 + gb) * 16 + 12 + gd] + TW0s[tok * 16 + 12 + gd];
                c0 = sigf(zf) * c0 + sigf(zi) * tanhf(zg);
                float h0v = sigf(zo) * tanhf(c0);
                h0st[(size_t)((s + 1) & 1) * BB * HH + (size_t)gb * HH + j] = (f16)h0v;
            }
            if (s >= 1) {   // layer 1, step t = s-1
                float zi = z1abuf[gb * 16 +  0 + gd] + z1abuf[(64 + gb) * 16 +  0 + gd] + z1bbuf[gb * 16 +  0 + gd] + b1s[ 0 + gd];
                float zf = z1abuf[gb * 16 +  4 + gd] + z1abuf[(64 + gb) * 16 +  4 + gd] + z1bbuf[gb * 16 +  4 + gd] + b1s[ 4 + gd];
                float zg = z1abuf[gb * 16 +  8 + gd] + z1abuf[(64 + gb) * 16 +  8 + gd] + z1bbuf[gb * 16 +  8 + gd] + b1s[ 8 + gd];
                float zo = z1abuf[gb * 16 + 12 + gd] + z1abuf[(64 + gb) * 16 + 12 + gd] + z1bbuf[gb * 16 + 12 + gd] + b1s[12 + gd];
                c1 = sigf(zf) * c1 + sigf(zi) * tanhf(zg);
                float h1v = sigf(zo) * tanhf(c1);
                h1st[(size_t)((s + 1) & 1) * BB * HH + (size_t)gb * HH + j] = (f16)h1v;
                h1seq[((size_t)gb * TT + (s - 1)) * HH + j] = (f16)h1v;
            }
        }
        grid.sync();
    }

    // ---------------- Phase C: logits = h1seq @ Wd + bd ----------------
    {
        const int r0 = g * 128;               // 128 (b,t)-rows per CU
        f32x4 accC[6];
        #pragma unroll
        for (int i = 0; i < 6; ++i) accC[i] = (f32x4){0.f, 0.f, 0.f, 0.f};

        for (int kc = 0; kc < 8; ++kc) {
            __syncthreads();
            // stage Wd K-chunk [128k][128n] -> LDS [n][k] f16 swizzled
            for (int idx = tid; idx < 128 * 128; idx += NTHREADS) {
                int kk = idx >> 7, nn = idx & 127;
                *(f16*)(smem + swz(OFF_WDC, nn, 256, kk)) = (f16)Wd[(size_t)(kc * 128 + kk) * 128 + nn];
            }
            __syncthreads();
            int ti = 0;
            for (int tile = wave; tile < 64; tile += 12, ++ti) {
                int mt = tile >> 3, nt = tile & 7;
                int arow = r0 + mt * 16 + (lane & 15);
                int kq = 8 * (lane >> 4);
                int nn = nt * 16 + (lane & 15);
                f32x4 acc = accC[ti];
                #pragma unroll
                for (int k4 = 0; k4 < 4; ++k4) {
                    int k = kc * 128 + k4 * 32 + kq;
                    f16x8 av = *(const f16x8*)&h1seq[(size_t)arow * HH + k];
                    f16x8 bv = *(const f16x8*)(smem + swz(OFF_WDC, nn, 256, k4 * 32 + kq));
                    acc = __builtin_amdgcn_mfma_f32_16x16x32_f16(av, bv, acc, 0, 0, 0);
                }
                accC[ti] = acc;
            }
        }
        int ti = 0;
        for (int tile = wave; tile < 64; tile += 12, ++ti) {
            int mt = tile >> 3, nt = tile & 7;
            int row0 = r0 + mt * 16 + (lane >> 4) * 4;
            int col  = nt * 16 + (lane & 15);
            float bdv = bd[col];
            #pragma unroll
            for (int r = 0; r < 4; ++r)
                out[(size_t)(row0 + r) * 128 + col] = accC[ti][r] + bdv;
        }
    }
}

extern "C" void kernel_launch(void* const* d_in, const int* in_sizes, int n_in,
                              void* d_out, int out_size, void* d_ws, size_t ws_size,
                              hipStream_t stream) {
    const int*   tokens = (const int*)d_in[0];
    const float* emb    = (const float*)d_in[1];
    const float* W0     = (const float*)d_in[2];
    const float* U0     = (const float*)d_in[3];
    const float* b0     = (const float*)d_in[4];
    const float* W1     = (const float*)d_in[5];
    const float* U1     = (const float*)d_in[6];
    const float* b1     = (const float*)d_in[7];
    const float* Wd     = (const float*)d_in[8];
    const float* bd     = (const float*)d_in[9];
    float* out = (float*)d_out;
    f16*   ws  = (f16*)d_ws;

    (void)hipFuncSetAttribute((const void*)lstm_fused,
                              hipFuncAttributeMaxDynamicSharedMemorySize, SMEM_BYTES);

    void* args[] = { &tokens, &emb, &W0, &U0, &b0, &W1, &U1, &b1, &Wd, &bd, &ws, &out };
    (void)hipLaunchCooperativeKernel((const void*)lstm_fused, dim3(NWG), dim3(NTHREADS),
                                     args, SMEM_BYTES, stream);
}

// Round 4
// 19754.001 us; speedup vs baseline: 1.0490x; 1.0490x over previous
//
#include <hip/hip_runtime.h>
#include <hip/hip_cooperative_groups.h>

namespace cg = cooperative_groups;

typedef _Float16 f16;
typedef __attribute__((ext_vector_type(8))) _Float16 f16x8;
typedef __attribute__((ext_vector_type(4))) float f32x4;

#define NWG      256
#define NTHREADS 768   // 12 waves
#define BB       64
#define TT       512
#define HH       1024
#define HD4      4096
#define VOCABB   128
#define EMBD     128

// LDS layout (bytes)
#define OFF_U0   0        // [16][1024] f16, XOR-swizzled rows : 32768
#define OFF_W1U1 32768    // [16][2048] f16, XOR-swizzled rows : 65536
#define OFF_TW0  98304    // [128][16] f32 : 8192
#define OFF_Z0   106560   // [2][64][16] f32 : 8192
#define OFF_Z1A  114752   // [2][64][16] f32 : 8192
#define OFF_Z1B  122944   // [64][16] f32 : 4096   (ends 127040)
#define OFF_WDC  98304    // phase-C alias: [128][128] f16 swizzled : 32768 (ends 131072)
#define SMEM_BYTES 131072

#define BARR_ELEMS (34 * 64)   // 16 gcnt + 16 gflag + rcnt + rflag, 256B-padded u32 slots

__device__ __forceinline__ float sigf(float x) { return 1.f / (1.f + __expf(-x)); }

// swizzled f16 LDS byte offset: row-major [rows][K], rowstride bytes, XOR bits 4..6
__device__ __forceinline__ int swz(int base, int row, int rowstride, int k) {
    return base + row * rowstride + ((2 * k) ^ ((row & 7) << 4));
}

__device__ __forceinline__ void spin_until(unsigned* p, unsigned epoch) {
    while (__hip_atomic_load(p, __ATOMIC_ACQUIRE, __HIP_MEMORY_SCOPE_AGENT) < epoch)
        __builtin_amdgcn_s_sleep(2);
}

// Two-level epoch barrier: 16 groups x 16 blocks. Monotonic counters (no reset).
__device__ __forceinline__ void gridbar(unsigned* barr, int g, int tid, unsigned epoch) {
    __syncthreads();   // drains each wave's stores (vmcnt 0) before tid0 publishes
    if (tid == 0) {
        const int gi = g >> 4;
        unsigned* gcnt  = barr + (size_t)gi * 64;
        unsigned* gflag = barr + (size_t)(16 + gi) * 64;
        unsigned* rcnt  = barr + (size_t)32 * 64;
        unsigned* rflag = barr + (size_t)33 * 64;
        unsigned old = __hip_atomic_fetch_add(gcnt, 1u, __ATOMIC_ACQ_REL, __HIP_MEMORY_SCOPE_AGENT);
        if (old == 16u * epoch - 1u) {           // last block of this group
            unsigned rold = __hip_atomic_fetch_add(rcnt, 1u, __ATOMIC_ACQ_REL, __HIP_MEMORY_SCOPE_AGENT);
            if (rold == 16u * epoch - 1u) {      // last group: release everyone
                __hip_atomic_store(rflag, epoch, __ATOMIC_RELEASE, __HIP_MEMORY_SCOPE_AGENT);
            } else {
                spin_until(rflag, epoch);
            }
            __hip_atomic_store(gflag, epoch, __ATOMIC_RELEASE, __HIP_MEMORY_SCOPE_AGENT);
        } else {
            spin_until(gflag, epoch);
        }
    }
    __syncthreads();
}

__global__ __launch_bounds__(NTHREADS, 3)
void lstm_fused(const int* __restrict__ tokens, const float* __restrict__ emb,
                const float* __restrict__ W0, const float* __restrict__ U0,
                const float* __restrict__ b0, const float* __restrict__ W1,
                const float* __restrict__ U1, const float* __restrict__ b1,
                const float* __restrict__ Wd, const float* __restrict__ bd,
                f16* __restrict__ wsh, float* __restrict__ out)
{
    extern __shared__ char smem[];
    cg::grid_group grid = cg::this_grid();
    const int g    = blockIdx.x;    // 0..255, owns gate-cols {gate*1024 + 4g + d}
    const int tid  = threadIdx.x;
    const int lane = tid & 63;
    const int wave = tid >> 6;

    // workspace (f16 units)
    f16* h1seq = wsh;                              // [B][T][H]
    f16* h0st  = wsh + (size_t)BB * TT * HH;       // [2][B][H]
    f16* h1st  = h0st + 2 * BB * HH;               // [2][B][H]
    unsigned* barr = (unsigned*)(h1st + 2 * BB * HH);  // barrier state (256B-aligned)

    // ---------------- Phase A: init ----------------
    {   // zero h-state double buffers (4*B*H f16 = 131072 u32; 512 u32 per WG)
        unsigned int* zp = (unsigned int*)h0st;
        for (int i = tid; i < 512; i += NTHREADS) zp[g * 512 + i] = 0u;
        if (g == 0)
            for (int i = tid; i < BARR_ELEMS; i += NTHREADS) barr[i] = 0u;
    }
    {   // stage U0 / [W1;U1] column slices into LDS as f16, transposed+swizzled
        const int c = tid & 15;                       // local col: gate*4 + delta
        const int orig = ((c >> 2) * HH) + 4 * g + (c & 3);
        for (int k = tid >> 4; k < HH; k += 48) {
            *(f16*)(smem + swz(OFF_U0, c, 2048, k))        = (f16)U0[(size_t)k * HD4 + orig];
            *(f16*)(smem + swz(OFF_W1U1, c, 4096, k))      = (f16)W1[(size_t)k * HD4 + orig];
            *(f16*)(smem + swz(OFF_W1U1, c, 4096, k + HH)) = (f16)U1[(size_t)k * HD4 + orig];
        }
    }
    // TW0 = emb @ W0 + b0, our 16-column slice (f32, exact)
    for (int idx = tid; idx < VOCABB * 16; idx += NTHREADS) {
        int v = idx >> 4, c = idx & 15;
        int orig = ((c >> 2) * HH) + 4 * g + (c & 3);
        float acc = b0[orig];
        for (int e = 0; e < EMBD; ++e)
            acc += emb[v * EMBD + e] * W0[(size_t)e * HD4 + orig];
        ((float*)(smem + OFF_TW0))[idx] = acc;
    }
    __syncthreads();
    grid.sync();      // publishes zeroed barrier state + h buffers (cg, one-time)

    // ---------------- Phase B: 513 pipelined supersteps ----------------
    float c0 = 0.f, c1 = 0.f;                 // cell states in gate-thread regs
    const int gb = tid >> 2, gd = tid & 3;    // gate thread: batch, delta
    float* z0buf  = (float*)(smem + OFF_Z0);
    float* z1abuf = (float*)(smem + OFF_Z1A);
    float* z1bbuf = (float*)(smem + OFF_Z1B);
    float* TW0s   = (float*)(smem + OFF_TW0);

    float b1r0 = 0.f, b1r1 = 0.f, b1r2 = 0.f, b1r3 = 0.f;
    if (tid < 256) {
        b1r0 = b1[0 * HH + 4 * g + gd];
        b1r1 = b1[1 * HH + 4 * g + gd];
        b1r2 = b1[2 * HH + 4 * g + gd];
        b1r3 = b1[3 * HH + 4 * g + gd];
    }

    for (int s = 0; s <= TT; ++s) {
        const f16* h0r = h0st + (size_t)(s & 1) * BB * HH;
        const f16* h1r = h1st + (size_t)(s & 1) * BB * HH;
        const int n  = lane & 15;
        const int kq = 8 * (lane >> 4);

        if (wave < 8) {
            // h0 path: shared A-fragment feeds U0 (layer0) and W1 (layer1)
            const int mt = wave & 3, kh = wave >> 2;
            const int arow = mt * 16 + (lane & 15);
            const f16* aptr = &h0r[(size_t)arow * HH + kh * 512 + kq];
            f16x8 av[16];
            #pragma unroll
            for (int ki = 0; ki < 16; ++ki)
                av[ki] = *(const f16x8*)(aptr + ki * 32);   // 16 loads in flight
            f32x4 a0 = {0.f, 0.f, 0.f, 0.f}, a1 = {0.f, 0.f, 0.f, 0.f};
            #pragma unroll
            for (int ki = 0; ki < 16; ++ki) {
                int k = kh * 512 + ki * 32 + kq;
                f16x8 bv0 = *(const f16x8*)(smem + swz(OFF_U0, n, 2048, k));
                a0 = __builtin_amdgcn_mfma_f32_16x16x32_f16(av[ki], bv0, a0, 0, 0, 0);
                f16x8 bv1 = *(const f16x8*)(smem + swz(OFF_W1U1, n, 4096, k));
                a1 = __builtin_amdgcn_mfma_f32_16x16x32_f16(av[ki], bv1, a1, 0, 0, 0);
            }
            int r0 = mt * 16 + (lane >> 4) * 4;
            #pragma unroll
            for (int r = 0; r < 4; ++r) {
                z0buf [(kh * 64 + r0 + r) * 16 + n] = a0[r];
                z1abuf[(kh * 64 + r0 + r) * 16 + n] = a1[r];
            }
        } else {
            // h1 path: h1_{t-1} @ U1
            const int mt = wave & 3;
            const int arow = mt * 16 + (lane & 15);
            const f16* aptr = &h1r[(size_t)arow * HH + kq];
            f32x4 a1 = {0.f, 0.f, 0.f, 0.f};
            #pragma unroll
            for (int half = 0; half < 2; ++half) {
                f16x8 av[16];
                #pragma unroll
                for (int ki = 0; ki < 16; ++ki)
                    av[ki] = *(const f16x8*)(aptr + half * 512 + ki * 32);
                #pragma unroll
                for (int ki = 0; ki < 16; ++ki) {
                    int k = half * 512 + ki * 32 + kq;
                    f16x8 bv = *(const f16x8*)(smem + swz(OFF_W1U1, n, 4096, k + HH));
                    a1 = __builtin_amdgcn_mfma_f32_16x16x32_f16(av[ki], bv, a1, 0, 0, 0);
                }
            }
            int r0 = mt * 16 + (lane >> 4) * 4;
            #pragma unroll
            for (int r = 0; r < 4; ++r) z1bbuf[(r0 + r) * 16 + n] = a1[r];
        }
        __syncthreads();

        if (tid < 256) {
            const int j = 4 * g + gd;
            if (s < TT) {   // layer 0, step t = s
                int tok = tokens[gb * TT + s];
                float zi = z0buf[gb * 16 +  0 + gd] + z0buf[(64 + gb) * 16 +  0 + gd] + TW0s[tok * 16 +  0 + gd];
                float zf = z0buf[gb * 16 +  4 + gd] + z0buf[(64 + gb) * 16 +  4 + gd] + TW0s[tok * 16 +  4 + gd];
                float zg = z0buf[gb * 16 +  8 + gd] + z0buf[(64 + gb) * 16 +  8 + gd] + TW0s[tok * 16 +  8 + gd];
                float zo = z0buf[gb * 16 + 12 + gd] + z0buf[(64 + gb) * 16 + 12 + gd] + TW0s[tok * 16 + 12 + gd];
                c0 = sigf(zf) * c0 + sigf(zi) * tanhf(zg);
                float h0v = sigf(zo) * tanhf(c0);
                h0st[(size_t)((s + 1) & 1) * BB * HH + (size_t)gb * HH + j] = (f16)h0v;
            }
            if (s >= 1) {   // layer 1, step t = s-1
                float zi = z1abuf[gb * 16 +  0 + gd] + z1abuf[(64 + gb) * 16 +  0 + gd] + z1bbuf[gb * 16 +  0 + gd] + b1r0;
                float zf = z1abuf[gb * 16 +  4 + gd] + z1abuf[(64 + gb) * 16 +  4 + gd] + z1bbuf[gb * 16 +  4 + gd] + b1r1;
                float zg = z1abuf[gb * 16 +  8 + gd] + z1abuf[(64 + gb) * 16 +  8 + gd] + z1bbuf[gb * 16 +  8 + gd] + b1r2;
                float zo = z1abuf[gb * 16 + 12 + gd] + z1abuf[(64 + gb) * 16 + 12 + gd] + z1bbuf[gb * 16 + 12 + gd] + b1r3;
                c1 = sigf(zf) * c1 + sigf(zi) * tanhf(zg);
                float h1v = sigf(zo) * tanhf(c1);
                h1st[(size_t)((s + 1) & 1) * BB * HH + (size_t)gb * HH + j] = (f16)h1v;
                h1seq[((size_t)gb * TT + (s - 1)) * HH + j] = (f16)h1v;
            }
        }
        gridbar(barr, g, tid, (unsigned)(s + 1));
    }

    // ---------------- Phase C: logits = h1seq @ Wd + bd ----------------
    {
        const int r0 = g * 128;               // 128 (b,t)-rows per CU
        f32x4 accC[6];
        #pragma unroll
        for (int i = 0; i < 6; ++i) accC[i] = (f32x4){0.f, 0.f, 0.f, 0.f};

        for (int kc = 0; kc < 8; ++kc) {
            __syncthreads();
            // stage Wd K-chunk [128k][128n] -> LDS [n][k] f16 swizzled
            for (int idx = tid; idx < 128 * 128; idx += NTHREADS) {
                int kk = idx >> 7, nn = idx & 127;
                *(f16*)(smem + swz(OFF_WDC, nn, 256, kk)) = (f16)Wd[(size_t)(kc * 128 + kk) * 128 + nn];
            }
            __syncthreads();
            int ti = 0;
            for (int tile = wave; tile < 64; tile += 12, ++ti) {
                int mt = tile >> 3, nt = tile & 7;
                int arow = r0 + mt * 16 + (lane & 15);
                int kq = 8 * (lane >> 4);
                int nn = nt * 16 + (lane & 15);
                f32x4 acc = accC[ti];
                #pragma unroll
                for (int k4 = 0; k4 < 4; ++k4) {
                    int k = kc * 128 + k4 * 32 + kq;
                    f16x8 av = *(const f16x8*)&h1seq[(size_t)arow * HH + k];
                    f16x8 bv = *(const f16x8*)(smem + swz(OFF_WDC, nn, 256, k4 * 32 + kq));
                    acc = __builtin_amdgcn_mfma_f32_16x16x32_f16(av, bv, acc, 0, 0, 0);
                }
                accC[ti] = acc;
            }
        }
        int ti = 0;
        for (int tile = wave; tile < 64; tile += 12, ++ti) {
            int mt = tile >> 3, nt = tile & 7;
            int row0 = r0 + mt * 16 + (lane >> 4) * 4;
            int col  = nt * 16 + (lane & 15);
            float bdv = bd[col];
            #pragma unroll
            for (int r = 0; r < 4; ++r)
                out[(size_t)(row0 + r) * 128 + col] = accC[ti][r] + bdv;
        }
    }
}

extern "C" void kernel_launch(void* const* d_in, const int* in_sizes, int n_in,
                              void* d_out, int out_size, void* d_ws, size_t ws_size,
                              hipStream_t stream) {
    const int*   tokens = (const int*)d_in[0];
    const float* emb    = (const float*)d_in[1];
    const float* W0     = (const float*)d_in[2];
    const float* U0     = (const float*)d_in[3];
    const float* b0     = (const float*)d_in[4];
    const float* W1     = (const float*)d_in[5];
    const float* U1     = (const float*)d_in[6];
    const float* b1     = (const float*)d_in[7];
    const float* Wd     = (const float*)d_in[8];
    const float* bd     = (const float*)d_in[9];
    float* out = (float*)d_out;
    f16*   ws  = (f16*)d_ws;

    (void)hipFuncSetAttribute((const void*)lstm_fused,
                              hipFuncAttributeMaxDynamicSharedMemorySize, SMEM_BYTES);

    void* args[] = { &tokens, &emb, &W0, &U0, &b0, &W1, &U1, &b1, &Wd, &bd, &ws, &out };
    (void)hipLaunchCooperativeKernel((const void*)lstm_fused, dim3(NWG), dim3(NTHREADS),
                                     args, SMEM_BYTES, stream);
}

// Round 6
// 9927.190 us; speedup vs baseline: 2.0875x; 1.9899x over previous
//
#include <hip/hip_runtime.h>
#include <hip/hip_cooperative_groups.h>

namespace cg = cooperative_groups;

typedef _Float16 f16;
typedef __attribute__((ext_vector_type(8))) _Float16 f16x8;
typedef __attribute__((ext_vector_type(4))) float f32x4;

#define NWG      256
#define NTHREADS 768   // 12 waves
#define BB       64
#define TT       512
#define HH       1024
#define HD4      4096
#define VOCABB   128
#define EMBD     128

// LDS layout (bytes)
#define OFF_U0   0        // [16][1024] f16, XOR-swizzled rows : 32768
#define OFF_W1U1 32768    // [16][2048] f16, XOR-swizzled rows : 65536
#define OFF_TW0  98304    // [128][16] f32 : 8192
#define OFF_Z0   106560   // [2][64][16] f32 : 8192
#define OFF_Z1A  114752   // [2][64][16] f32 : 8192
#define OFF_Z1B  122944   // [64][16] f32 : 4096   (ends 127040)
#define OFF_WDC  98304    // phase-C alias: [128][128] f16 swizzled : 32768 (ends 131072)
#define SMEM_BYTES 131072

#define BARR_ELEMS (34 * 64)   // 16 gcnt + 16 gflag + rcnt + rflag, 256B-padded u32 slots

__device__ __forceinline__ float sigf(float x) { return 1.f / (1.f + __expf(-x)); }

// swizzled f16 LDS byte offset: row-major [rows][K], rowstride bytes, XOR bits 4..6
__device__ __forceinline__ int swz(int base, int row, int rowstride, int k) {
    return base + row * rowstride + ((2 * k) ^ ((row & 7) << 4));
}

// RELAXED spin — compiles to a plain L3-side (sc1) load, NO buffer_inv per poll.
__device__ __forceinline__ void spin_until(unsigned* p, unsigned epoch) {
    while (__hip_atomic_load(p, __ATOMIC_RELAXED, __HIP_MEMORY_SCOPE_AGENT) < epoch)
        __builtin_amdgcn_s_sleep(1);
}

// Two-level epoch barrier: 16 groups x 16 blocks. Monotonic counters (no reset).
// Fence-based sync: ONE release fence + ONE acquire fence per block per barrier;
// all atomics relaxed (no per-op L2 writeback/invalidate).
__device__ __forceinline__ void gridbar(unsigned* barr, int g, int tid, unsigned epoch) {
    __syncthreads();   // drains each wave's stores (vmcnt 0) before tid0 publishes
    if (tid == 0) {
        __builtin_amdgcn_fence(__ATOMIC_RELEASE, "agent");   // wbl2: block's h-stores -> coherence point
        const int gi = g >> 4;
        unsigned* gcnt  = barr + (size_t)gi * 64;
        unsigned* gflag = barr + (size_t)(16 + gi) * 64;
        unsigned* rcnt  = barr + (size_t)32 * 64;
        unsigned* rflag = barr + (size_t)33 * 64;
        unsigned old = __hip_atomic_fetch_add(gcnt, 1u, __ATOMIC_RELAXED, __HIP_MEMORY_SCOPE_AGENT);
        if (old == 16u * epoch - 1u) {           // last block of this group
            unsigned rold = __hip_atomic_fetch_add(rcnt, 1u, __ATOMIC_RELAXED, __HIP_MEMORY_SCOPE_AGENT);
            if (rold == 16u * epoch - 1u) {      // last group: release everyone
                __hip_atomic_store(rflag, epoch, __ATOMIC_RELAXED, __HIP_MEMORY_SCOPE_AGENT);
            } else {
                spin_until(rflag, epoch);
            }
            __hip_atomic_store(gflag, epoch, __ATOMIC_RELAXED, __HIP_MEMORY_SCOPE_AGENT);
        } else {
            spin_until(gflag, epoch);
        }
        __builtin_amdgcn_fence(__ATOMIC_ACQUIRE, "agent");   // ONE buffer_inv per block per step
    }
    __syncthreads();
}

__global__ __launch_bounds__(NTHREADS, 3)
void lstm_fused(const int* __restrict__ tokens, const float* __restrict__ emb,
                const float* __restrict__ W0, const float* __restrict__ U0,
                const float* __restrict__ b0, const float* __restrict__ W1,
                const float* __restrict__ U1, const float* __restrict__ b1,
                const float* __restrict__ Wd, const float* __restrict__ bd,
                f16* __restrict__ wsh, float* __restrict__ out)
{
    extern __shared__ char smem[];
    cg::grid_group grid = cg::this_grid();
    const int g    = blockIdx.x;    // 0..255, owns gate-cols {gate*1024 + 4g + d}
    const int tid  = threadIdx.x;
    const int lane = tid & 63;
    const int wave = tid >> 6;

    // workspace (f16 units)
    f16* h1seq = wsh;                              // [B][T][H]
    f16* h0st  = wsh + (size_t)BB * TT * HH;       // [2][B][H]
    f16* h1st  = h0st + 2 * BB * HH;               // [2][B][H]
    unsigned* barr = (unsigned*)(h1st + 2 * BB * HH);  // barrier state (256B-aligned)

    // ---------------- Phase A: init ----------------
    {   // zero h-state double buffers (4*B*H f16 = 131072 u32; 512 u32 per WG)
        unsigned int* zp = (unsigned int*)h0st;
        for (int i = tid; i < 512; i += NTHREADS) zp[g * 512 + i] = 0u;
        if (g == 0)
            for (int i = tid; i < BARR_ELEMS; i += NTHREADS) barr[i] = 0u;
    }
    {   // stage U0 / [W1;U1] column slices into LDS as f16, transposed+swizzled
        const int c = tid & 15;                       // local col: gate*4 + delta
        const int orig = ((c >> 2) * HH) + 4 * g + (c & 3);
        for (int k = tid >> 4; k < HH; k += 48) {
            *(f16*)(smem + swz(OFF_U0, c, 2048, k))        = (f16)U0[(size_t)k * HD4 + orig];
            *(f16*)(smem + swz(OFF_W1U1, c, 4096, k))      = (f16)W1[(size_t)k * HD4 + orig];
            *(f16*)(smem + swz(OFF_W1U1, c, 4096, k + HH)) = (f16)U1[(size_t)k * HD4 + orig];
        }
    }
    // TW0 = emb @ W0 + b0, our 16-column slice (f32, exact)
    for (int idx = tid; idx < VOCABB * 16; idx += NTHREADS) {
        int v = idx >> 4, c = idx & 15;
        int orig = ((c >> 2) * HH) + 4 * g + (c & 3);
        float acc = b0[orig];
        for (int e = 0; e < EMBD; ++e)
            acc += emb[v * EMBD + e] * W0[(size_t)e * HD4 + orig];
        ((float*)(smem + OFF_TW0))[idx] = acc;
    }
    __syncthreads();
    grid.sync();      // publishes zeroed barrier state + h buffers (cg, one-time)

    // ---------------- Phase B: 513 pipelined supersteps ----------------
    float c0 = 0.f, c1 = 0.f;                 // cell states in gate-thread regs
    const int gb = tid >> 2, gd = tid & 3;    // gate thread: batch, delta
    float* z0buf  = (float*)(smem + OFF_Z0);
    float* z1abuf = (float*)(smem + OFF_Z1A);
    float* z1bbuf = (float*)(smem + OFF_Z1B);
    float* TW0s   = (float*)(smem + OFF_TW0);

    float b1r0 = 0.f, b1r1 = 0.f, b1r2 = 0.f, b1r3 = 0.f;
    if (tid < 256) {
        b1r0 = b1[0 * HH + 4 * g + gd];
        b1r1 = b1[1 * HH + 4 * g + gd];
        b1r2 = b1[2 * HH + 4 * g + gd];
        b1r3 = b1[3 * HH + 4 * g + gd];
    }

    for (int s = 0; s <= TT; ++s) {
        const f16* h0r = h0st + (size_t)(s & 1) * BB * HH;
        const f16* h1r = h1st + (size_t)(s & 1) * BB * HH;
        const int n  = lane & 15;
        const int kq = 8 * (lane >> 4);

        if (wave < 8) {
            // h0 path: shared A-fragment feeds U0 (layer0) and W1 (layer1)
            const int mt = wave & 3, kh = wave >> 2;
            const int arow = mt * 16 + (lane & 15);
            const f16* aptr = &h0r[(size_t)arow * HH + kh * 512 + kq];
            f16x8 av[16];
            #pragma unroll
            for (int ki = 0; ki < 16; ++ki)
                av[ki] = *(const f16x8*)(aptr + ki * 32);   // 16 loads in flight
            f32x4 a0 = {0.f, 0.f, 0.f, 0.f}, a1 = {0.f, 0.f, 0.f, 0.f};
            #pragma unroll
            for (int ki = 0; ki < 16; ++ki) {
                int k = kh * 512 + ki * 32 + kq;
                f16x8 bv0 = *(const f16x8*)(smem + swz(OFF_U0, n, 2048, k));
                a0 = __builtin_amdgcn_mfma_f32_16x16x32_f16(av[ki], bv0, a0, 0, 0, 0);
                f16x8 bv1 = *(const f16x8*)(smem + swz(OFF_W1U1, n, 4096, k));
                a1 = __builtin_amdgcn_mfma_f32_16x16x32_f16(av[ki], bv1, a1, 0, 0, 0);
            }
            int r0 = mt * 16 + (lane >> 4) * 4;
            #pragma unroll
            for (int r = 0; r < 4; ++r) {
                z0buf [(kh * 64 + r0 + r) * 16 + n] = a0[r];
                z1abuf[(kh * 64 + r0 + r) * 16 + n] = a1[r];
            }
        } else {
            // h1 path: h1_{t-1} @ U1
            const int mt = wave & 3;
            const int arow = mt * 16 + (lane & 15);
            const f16* aptr = &h1r[(size_t)arow * HH + kq];
            f32x4 a1 = {0.f, 0.f, 0.f, 0.f};
            #pragma unroll
            for (int half = 0; half < 2; ++half) {
                f16x8 av[16];
                #pragma unroll
                for (int ki = 0; ki < 16; ++ki)
                    av[ki] = *(const f16x8*)(aptr + half * 512 + ki * 32);
                #pragma unroll
                for (int ki = 0; ki < 16; ++ki) {
                    int k = half * 512 + ki * 32 + kq;
                    f16x8 bv = *(const f16x8*)(smem + swz(OFF_W1U1, n, 4096, k + HH));
                    a1 = __builtin_amdgcn_mfma_f32_16x16x32_f16(av[ki], bv, a1, 0, 0, 0);
                }
            }
            int r0 = mt * 16 + (lane >> 4) * 4;
            #pragma unroll
            for (int r = 0; r < 4; ++r) z1bbuf[(r0 + r) * 16 + n] = a1[r];
        }
        __syncthreads();

        if (tid < 256) {
            const int j = 4 * g + gd;
            if (s < TT) {   // layer 0, step t = s
                int tok = tokens[gb * TT + s];
                float zi = z0buf[gb * 16 +  0 + gd] + z0buf[(64 + gb) * 16 +  0 + gd] + TW0s[tok * 16 +  0 + gd];
                float zf = z0buf[gb * 16 +  4 + gd] + z0buf[(64 + gb) * 16 +  4 + gd] + TW0s[tok * 16 +  4 + gd];
                float zg = z0buf[gb * 16 +  8 + gd] + z0buf[(64 + gb) * 16 +  8 + gd] + TW0s[tok * 16 +  8 + gd];
                float zo = z0buf[gb * 16 + 12 + gd] + z0buf[(64 + gb) * 16 + 12 + gd] + TW0s[tok * 16 + 12 + gd];
                c0 = sigf(zf) * c0 + sigf(zi) * tanhf(zg);
                float h0v = sigf(zo) * tanhf(c0);
                h0st[(size_t)((s + 1) & 1) * BB * HH + (size_t)gb * HH + j] = (f16)h0v;
            }
            if (s >= 1) {   // layer 1, step t = s-1
                float zi = z1abuf[gb * 16 +  0 + gd] + z1abuf[(64 + gb) * 16 +  0 + gd] + z1bbuf[gb * 16 +  0 + gd] + b1r0;
                float zf = z1abuf[gb * 16 +  4 + gd] + z1abuf[(64 + gb) * 16 +  4 + gd] + z1bbuf[gb * 16 +  4 + gd] + b1r1;
                float zg = z1abuf[gb * 16 +  8 + gd] + z1abuf[(64 + gb) * 16 +  8 + gd] + z1bbuf[gb * 16 +  8 + gd] + b1r2;
                float zo = z1abuf[gb * 16 + 12 + gd] + z1abuf[(64 + gb) * 16 + 12 + gd] + z1bbuf[gb * 16 + 12 + gd] + b1r3;
                c1 = sigf(zf) * c1 + sigf(zi) * tanhf(zg);
                float h1v = sigf(zo) * tanhf(c1);
                h1st[(size_t)((s + 1) & 1) * BB * HH + (size_t)gb * HH + j] = (f16)h1v;
                h1seq[((size_t)gb * TT + (s - 1)) * HH + j] = (f16)h1v;
            }
        }
        gridbar(barr, g, tid, (unsigned)(s + 1));
    }

    // ---------------- Phase C: logits = h1seq @ Wd + bd ----------------
    {
        const int r0 = g * 128;               // 128 (b,t)-rows per CU
        f32x4 accC[6];
        #pragma unroll
        for (int i = 0; i < 6; ++i) accC[i] = (f32x4){0.f, 0.f, 0.f, 0.f};

        for (int kc = 0; kc < 8; ++kc) {
            __syncthreads();
            // stage Wd K-chunk [128k][128n] -> LDS [n][k] f16 swizzled
            for (int idx = tid; idx < 128 * 128; idx += NTHREADS) {
                int kk = idx >> 7, nn = idx & 127;
                *(f16*)(smem + swz(OFF_WDC, nn, 256, kk)) = (f16)Wd[(size_t)(kc * 128 + kk) * 128 + nn];
            }
            __syncthreads();
            int ti = 0;
            for (int tile = wave; tile < 64; tile += 12, ++ti) {
                int mt = tile >> 3, nt = tile & 7;
                int arow = r0 + mt * 16 + (lane & 15);
                int kq = 8 * (lane >> 4);
                int nn = nt * 16 + (lane & 15);
                f32x4 acc = accC[ti];
                #pragma unroll
                for (int k4 = 0; k4 < 4; ++k4) {
                    int k = kc * 128 + k4 * 32 + kq;
                    f16x8 av = *(const f16x8*)&h1seq[(size_t)arow * HH + k];
                    f16x8 bv = *(const f16x8*)(smem + swz(OFF_WDC, nn, 256, k4 * 32 + kq));
                    acc = __builtin_amdgcn_mfma_f32_16x16x32_f16(av, bv, acc, 0, 0, 0);
                }
                accC[ti] = acc;
            }
        }
        int ti = 0;
        for (int tile = wave; tile < 64; tile += 12, ++ti) {
            int mt = tile >> 3, nt = tile & 7;
            int row0 = r0 + mt * 16 + (lane >> 4) * 4;
            int col  = nt * 16 + (lane & 15);
            float bdv = bd[col];
            #pragma unroll
            for (int r = 0; r < 4; ++r)
                out[(size_t)(row0 + r) * 128 + col] = accC[ti][r] + bdv;
        }
    }
}

extern "C" void kernel_launch(void* const* d_in, const int* in_sizes, int n_in,
                              void* d_out, int out_size, void* d_ws, size_t ws_size,
                              hipStream_t stream) {
    const int*   tokens = (const int*)d_in[0];
    const float* emb    = (const float*)d_in[1];
    const float* W0     = (const float*)d_in[2];
    const float* U0     = (const float*)d_in[3];
    const float* b0     = (const float*)d_in[4];
    const float* W1     = (const float*)d_in[5];
    const float* U1     = (const float*)d_in[6];
    const float* b1     = (const float*)d_in[7];
    const float* Wd     = (const float*)d_in[8];
    const float* bd     = (const float*)d_in[9];
    float* out = (float*)d_out;
    f16*   ws  = (f16*)d_ws;

    (void)hipFuncSetAttribute((const void*)lstm_fused,
                              hipFuncAttributeMaxDynamicSharedMemorySize, SMEM_BYTES);

    void* args[] = { &tokens, &emb, &W0, &U0, &b0, &W1, &U1, &b1, &Wd, &bd, &ws, &out };
    (void)hipLaunchCooperativeKernel((const void*)lstm_fused, dim3(NWG), dim3(NTHREADS),
                                     args, SMEM_BYTES, stream);
}

// Round 7
// 6432.597 us; speedup vs baseline: 3.2215x; 1.5433x over previous
//
#include <hip/hip_runtime.h>
#include <hip/hip_cooperative_groups.h>

namespace cg = cooperative_groups;

typedef _Float16 f16;
typedef __attribute__((ext_vector_type(8))) _Float16 f16x8;
typedef __attribute__((ext_vector_type(4))) float f32x4;

#define NWG      256
#define NTHREADS 768   // 12 waves
#define BB       64
#define TT       512
#define HH       1024
#define HD4      4096
#define VOCABB   128
#define EMBD     128

// LDS layout (bytes)
#define OFF_U0   0        // [16][1024] f16, XOR-swizzled rows : 32768
#define OFF_W1U1 32768    // [16][2048] f16, XOR-swizzled rows : 65536
#define OFF_TW0  98304    // [128][16] f32 : 8192
#define OFF_Z0   106560   // [2][64][16] f32 : 8192
#define OFF_Z1A  114752   // [2][64][16] f32 : 8192
#define OFF_Z1B  122944   // [64][16] f32 : 4096   (ends 127040)
#define OFF_WDC  98304    // phase-C alias: [128][128] f16 swizzled : 32768 (ends 131072)
#define SMEM_BYTES 131072

#define BARR_ELEMS (34 * 64)   // 16 gcnt + 16 gflag + rcnt (+spare), 256B-padded u32 slots

__device__ __forceinline__ float sigf(float x) { return 1.f / (1.f + __expf(-x)); }

// swizzled f16 LDS byte offset: row-major [rows][K], rowstride bytes, XOR bits 4..6
__device__ __forceinline__ int swz(int base, int row, int rowstride, int k) {
    return base + row * rowstride + ((2 * k) ^ ((row & 7) << 4));
}

// Coherence-point (L3-direct) 16B load: bypasses L1/L2 (sc0 sc1) -> no stale data,
// no buffer_inv needed anywhere in the hot loop.
__device__ __forceinline__ f16x8 ld16sc(const f16* p) {
    f16x8 r;
    asm volatile("global_load_dwordx4 %0, %1, off sc0 sc1"
                 : "=v"(r) : "v"(p) : "memory");
    return r;
}

// Coherence-point 2B store: write-through to L3 (sc0 sc1), no dirty L2 line,
// no buffer_wbl2 needed. vmcnt ack = committed at coherence point.
__device__ __forceinline__ void st2sc(f16* p, float v) {
    f16 h = (f16)v;
    unsigned short u;
    __builtin_memcpy(&u, &h, 2);
    asm volatile("global_store_short %0, %1, off sc0 sc1"
                 :: "v"(p), "v"(u) : "memory");
}

// RELAXED spin — plain coherence-point atomic load, NO cache maintenance per poll.
__device__ __forceinline__ void spin_until(unsigned* p, unsigned epoch) {
    while (__hip_atomic_load(p, __ATOMIC_RELAXED, __HIP_MEMORY_SCOPE_AGENT) < epoch)
        __builtin_amdgcn_s_sleep(1);
}

// Two-level epoch barrier, ZERO fences: data path is sc0sc1 (coherence point),
// so no wbl2/inv required. Root broadcasts all 16 group flags (one spin hop only).
__device__ __forceinline__ void gridbar(unsigned* barr, int g, int tid, unsigned epoch) {
    asm volatile("s_waitcnt vmcnt(0)" ::: "memory");  // this wave's sc1 stores committed
    __syncthreads();
    if (tid == 0) {
        const int gi = g >> 4;
        unsigned* gcnt  = barr + (size_t)gi * 64;
        unsigned* gflag = barr + (size_t)(16 + gi) * 64;
        unsigned* rcnt  = barr + (size_t)32 * 64;
        unsigned old = __hip_atomic_fetch_add(gcnt, 1u, __ATOMIC_RELAXED, __HIP_MEMORY_SCOPE_AGENT);
        if (old == 16u * epoch - 1u) {           // last block of this group
            unsigned rold = __hip_atomic_fetch_add(rcnt, 1u, __ATOMIC_RELAXED, __HIP_MEMORY_SCOPE_AGENT);
            if (rold == 16u * epoch - 1u) {      // last block overall: release all groups
                #pragma unroll
                for (int gg = 0; gg < 16; ++gg)
                    __hip_atomic_store(barr + (size_t)(16 + gg) * 64, epoch,
                                       __ATOMIC_RELAXED, __HIP_MEMORY_SCOPE_AGENT);
            }
        }
        spin_until(gflag, epoch);
    }
    __syncthreads();
}

__global__ __launch_bounds__(NTHREADS, 3)
void lstm_fused(const int* __restrict__ tokens, const float* __restrict__ emb,
                const float* __restrict__ W0, const float* __restrict__ U0,
                const float* __restrict__ b0, const float* __restrict__ W1,
                const float* __restrict__ U1, const float* __restrict__ b1,
                const float* __restrict__ Wd, const float* __restrict__ bd,
                f16* __restrict__ wsh, float* __restrict__ out)
{
    extern __shared__ char smem[];
    cg::grid_group grid = cg::this_grid();
    const int g    = blockIdx.x;    // 0..255, owns gate-cols {gate*1024 + 4g + d}
    const int tid  = threadIdx.x;
    const int lane = tid & 63;
    const int wave = tid >> 6;

    // workspace (f16 units)
    f16* h1seq = wsh;                              // [B][T][H]
    f16* h0st  = wsh + (size_t)BB * TT * HH;       // [2][B][H]
    f16* h1st  = h0st + 2 * BB * HH;               // [2][B][H]
    unsigned* barr = (unsigned*)(h1st + 2 * BB * HH);  // barrier state (256B-aligned)

    // ---------------- Phase A: init ----------------
    {   // zero h-state double buffers (4*B*H f16 = 131072 u32; 512 u32 per WG)
        unsigned int* zp = (unsigned int*)h0st;
        for (int i = tid; i < 512; i += NTHREADS) zp[g * 512 + i] = 0u;
        if (g == 0)
            for (int i = tid; i < BARR_ELEMS; i += NTHREADS) barr[i] = 0u;
    }
    {   // stage U0 / [W1;U1] column slices into LDS as f16, transposed+swizzled
        const int c = tid & 15;                       // local col: gate*4 + delta
        const int orig = ((c >> 2) * HH) + 4 * g + (c & 3);
        for (int k = tid >> 4; k < HH; k += 48) {
            *(f16*)(smem + swz(OFF_U0, c, 2048, k))        = (f16)U0[(size_t)k * HD4 + orig];
            *(f16*)(smem + swz(OFF_W1U1, c, 4096, k))      = (f16)W1[(size_t)k * HD4 + orig];
            *(f16*)(smem + swz(OFF_W1U1, c, 4096, k + HH)) = (f16)U1[(size_t)k * HD4 + orig];
        }
    }
    // TW0 = emb @ W0 + b0, our 16-column slice (f32, exact)
    for (int idx = tid; idx < VOCABB * 16; idx += NTHREADS) {
        int v = idx >> 4, c = idx & 15;
        int orig = ((c >> 2) * HH) + 4 * g + (c & 3);
        float acc = b0[orig];
        for (int e = 0; e < EMBD; ++e)
            acc += emb[v * EMBD + e] * W0[(size_t)e * HD4 + orig];
        ((float*)(smem + OFF_TW0))[idx] = acc;
    }
    __syncthreads();
    grid.sync();      // one-time full release/acquire: publishes zeros + barrier state

    // ---------------- Phase B: 513 pipelined supersteps ----------------
    float c0 = 0.f, c1 = 0.f;                 // cell states in gate-thread regs
    const int gb = tid >> 2, gd = tid & 3;    // gate thread: batch, delta
    float* z0buf  = (float*)(smem + OFF_Z0);
    float* z1abuf = (float*)(smem + OFF_Z1A);
    float* z1bbuf = (float*)(smem + OFF_Z1B);
    float* TW0s   = (float*)(smem + OFF_TW0);

    float b1r0 = 0.f, b1r1 = 0.f, b1r2 = 0.f, b1r3 = 0.f;
    if (tid < 256) {
        b1r0 = b1[0 * HH + 4 * g + gd];
        b1r1 = b1[1 * HH + 4 * g + gd];
        b1r2 = b1[2 * HH + 4 * g + gd];
        b1r3 = b1[3 * HH + 4 * g + gd];
    }

    for (int s = 0; s <= TT; ++s) {
        const f16* h0r = h0st + (size_t)(s & 1) * BB * HH;
        const f16* h1r = h1st + (size_t)(s & 1) * BB * HH;
        const int n  = lane & 15;
        const int kq = 8 * (lane >> 4);

        if (wave < 8) {
            // h0 path: shared A-fragment feeds U0 (layer0) and W1 (layer1)
            const int mt = wave & 3, kh = wave >> 2;
            const int arow = mt * 16 + (lane & 15);
            const f16* aptr = &h0r[(size_t)arow * HH + kh * 512 + kq];
            f16x8 av[16];
            #pragma unroll
            for (int ki = 0; ki < 16; ++ki)
                av[ki] = ld16sc(aptr + ki * 32);    // 16 L3-direct loads in flight
            asm volatile("s_waitcnt vmcnt(0)" ::: "memory");
            __builtin_amdgcn_sched_barrier(0);
            f32x4 a0 = {0.f, 0.f, 0.f, 0.f}, a1 = {0.f, 0.f, 0.f, 0.f};
            #pragma unroll
            for (int ki = 0; ki < 16; ++ki) {
                int k = kh * 512 + ki * 32 + kq;
                f16x8 bv0 = *(const f16x8*)(smem + swz(OFF_U0, n, 2048, k));
                a0 = __builtin_amdgcn_mfma_f32_16x16x32_f16(av[ki], bv0, a0, 0, 0, 0);
                f16x8 bv1 = *(const f16x8*)(smem + swz(OFF_W1U1, n, 4096, k));
                a1 = __builtin_amdgcn_mfma_f32_16x16x32_f16(av[ki], bv1, a1, 0, 0, 0);
            }
            int r0 = mt * 16 + (lane >> 4) * 4;
            #pragma unroll
            for (int r = 0; r < 4; ++r) {
                z0buf [(kh * 64 + r0 + r) * 16 + n] = a0[r];
                z1abuf[(kh * 64 + r0 + r) * 16 + n] = a1[r];
            }
        } else {
            // h1 path: h1_{t-1} @ U1
            const int mt = wave & 3;
            const int arow = mt * 16 + (lane & 15);
            const f16* aptr = &h1r[(size_t)arow * HH + kq];
            f32x4 a1 = {0.f, 0.f, 0.f, 0.f};
            #pragma unroll
            for (int half = 0; half < 2; ++half) {
                f16x8 av[16];
                #pragma unroll
                for (int ki = 0; ki < 16; ++ki)
                    av[ki] = ld16sc(aptr + half * 512 + ki * 32);
                asm volatile("s_waitcnt vmcnt(0)" ::: "memory");
                __builtin_amdgcn_sched_barrier(0);
                #pragma unroll
                for (int ki = 0; ki < 16; ++ki) {
                    int k = half * 512 + ki * 32 + kq;
                    f16x8 bv = *(const f16x8*)(smem + swz(OFF_W1U1, n, 4096, k + HH));
                    a1 = __builtin_amdgcn_mfma_f32_16x16x32_f16(av[ki], bv, a1, 0, 0, 0);
                }
            }
            int r0 = mt * 16 + (lane >> 4) * 4;
            #pragma unroll
            for (int r = 0; r < 4; ++r) z1bbuf[(r0 + r) * 16 + n] = a1[r];
        }
        __syncthreads();

        if (tid < 256) {
            const int j = 4 * g + gd;
            if (s < TT) {   // layer 0, step t = s
                int tok = tokens[gb * TT + s];
                float zi = z0buf[gb * 16 +  0 + gd] + z0buf[(64 + gb) * 16 +  0 + gd] + TW0s[tok * 16 +  0 + gd];
                float zf = z0buf[gb * 16 +  4 + gd] + z0buf[(64 + gb) * 16 +  4 + gd] + TW0s[tok * 16 +  4 + gd];
                float zg = z0buf[gb * 16 +  8 + gd] + z0buf[(64 + gb) * 16 +  8 + gd] + TW0s[tok * 16 +  8 + gd];
                float zo = z0buf[gb * 16 + 12 + gd] + z0buf[(64 + gb) * 16 + 12 + gd] + TW0s[tok * 16 + 12 + gd];
                c0 = sigf(zf) * c0 + sigf(zi) * tanhf(zg);
                float h0v = sigf(zo) * tanhf(c0);
                st2sc(&h0st[(size_t)((s + 1) & 1) * BB * HH + (size_t)gb * HH + j], h0v);
            }
            if (s >= 1) {   // layer 1, step t = s-1
                float zi = z1abuf[gb * 16 +  0 + gd] + z1abuf[(64 + gb) * 16 +  0 + gd] + z1bbuf[gb * 16 +  0 + gd] + b1r0;
                float zf = z1abuf[gb * 16 +  4 + gd] + z1abuf[(64 + gb) * 16 +  4 + gd] + z1bbuf[gb * 16 +  4 + gd] + b1r1;
                float zg = z1abuf[gb * 16 +  8 + gd] + z1abuf[(64 + gb) * 16 +  8 + gd] + z1bbuf[gb * 16 +  8 + gd] + b1r2;
                float zo = z1abuf[gb * 16 + 12 + gd] + z1abuf[(64 + gb) * 16 + 12 + gd] + z1bbuf[gb * 16 + 12 + gd] + b1r3;
                c1 = sigf(zf) * c1 + sigf(zi) * tanhf(zg);
                float h1v = sigf(zo) * tanhf(c1);
                st2sc(&h1st[(size_t)((s + 1) & 1) * BB * HH + (size_t)gb * HH + j], h1v);
                st2sc(&h1seq[((size_t)gb * TT + (s - 1)) * HH + j], h1v);
            }
        }
        gridbar(barr, g, tid, (unsigned)(s + 1));
    }

    // ---------------- Phase C: logits = h1seq @ Wd + bd ----------------
    // h1seq was written sc0sc1 (no L2 allocation anywhere) -> plain cached reads
    // below fetch fresh data from L3; no fence needed.
    {
        const int r0 = g * 128;               // 128 (b,t)-rows per CU
        f32x4 accC[6];
        #pragma unroll
        for (int i = 0; i < 6; ++i) accC[i] = (f32x4){0.f, 0.f, 0.f, 0.f};

        for (int kc = 0; kc < 8; ++kc) {
            __syncthreads();
            // stage Wd K-chunk [128k][128n] -> LDS [n][k] f16 swizzled
            for (int idx = tid; idx < 128 * 128; idx += NTHREADS) {
                int kk = idx >> 7, nn = idx & 127;
                *(f16*)(smem + swz(OFF_WDC, nn, 256, kk)) = (f16)Wd[(size_t)(kc * 128 + kk) * 128 + nn];
            }
            __syncthreads();
            int ti = 0;
            for (int tile = wave; tile < 64; tile += 12, ++ti) {
                int mt = tile >> 3, nt = tile & 7;
                int arow = r0 + mt * 16 + (lane & 15);
                int kq = 8 * (lane >> 4);
                int nn = nt * 16 + (lane & 15);
                f32x4 acc = accC[ti];
                #pragma unroll
                for (int k4 = 0; k4 < 4; ++k4) {
                    int k = kc * 128 + k4 * 32 + kq;
                    f16x8 av = *(const f16x8*)&h1seq[(size_t)arow * HH + k];
                    f16x8 bv = *(const f16x8*)(smem + swz(OFF_WDC, nn, 256, k4 * 32 + kq));
                    acc = __builtin_amdgcn_mfma_f32_16x16x32_f16(av, bv, acc, 0, 0, 0);
                }
                accC[ti] = acc;
            }
        }
        int ti = 0;
        for (int tile = wave; tile < 64; tile += 12, ++ti) {
            int mt = tile >> 3, nt = tile & 7;
            int row0 = r0 + mt * 16 + (lane >> 4) * 4;
            int col  = nt * 16 + (lane & 15);
            float bdv = bd[col];
            #pragma unroll
            for (int r = 0; r < 4; ++r)
                out[(size_t)(row0 + r) * 128 + col] = accC[ti][r] + bdv;
        }
    }
}

extern "C" void kernel_launch(void* const* d_in, const int* in_sizes, int n_in,
                              void* d_out, int out_size, void* d_ws, size_t ws_size,
                              hipStream_t stream) {
    const int*   tokens = (const int*)d_in[0];
    const float* emb    = (const float*)d_in[1];
    const float* W0     = (const float*)d_in[2];
    const float* U0     = (const float*)d_in[3];
    const float* b0     = (const float*)d_in[4];
    const float* W1     = (const float*)d_in[5];
    const float* U1     = (const float*)d_in[6];
    const float* b1     = (const float*)d_in[7];
    const float* Wd     = (const float*)d_in[8];
    const float* bd     = (const float*)d_in[9];
    float* out = (float*)d_out;
    f16*   ws  = (f16*)d_ws;

    (void)hipFuncSetAttribute((const void*)lstm_fused,
                              hipFuncAttributeMaxDynamicSharedMemorySize, SMEM_BYTES);

    void* args[] = { &tokens, &emb, &W0, &U0, &b0, &W1, &U1, &b1, &Wd, &bd, &ws, &out };
    (void)hipLaunchCooperativeKernel((const void*)lstm_fused, dim3(NWG), dim3(NTHREADS),
                                     args, SMEM_BYTES, stream);
}